// Round 2
// baseline (2009.439 us; speedup 1.0000x reference)
//
#include <hip/hip_runtime.h>

#define B_ 8
#define L_ 16
#define H_ 16
#define D_ 64
#define DM 1024
#define S_ 8192

// ---------------- P1/P5: split-K GEMM, M=128, BN=64, BK=32 ----------------
__global__ void __launch_bounds__(256) gemm_splitk_kernel(
    const float* __restrict__ A, const float* __restrict__ W,
    float* __restrict__ part, int lda, int ldw, int Kchunk)
{
  const int c0 = blockIdx.x * 64;
  const int k0 = blockIdx.y * Kchunk;
  const int t  = threadIdx.x;
  __shared__ float xs[32][132];   // A tile transposed, padded
  __shared__ float wsm[32][64];   // W tile
  float acc[8][4];
  #pragma unroll
  for (int i = 0; i < 8; ++i)
    #pragma unroll
    for (int j = 0; j < 4; ++j) acc[i][j] = 0.f;
  const int rg = t >> 4, cg = t & 15;
  const int r0 = rg * 8, ct0 = cg * 4;
  for (int ks = 0; ks < Kchunk; ks += 32) {
    __syncthreads();
    #pragma unroll
    for (int i = 0; i < 4; ++i) {           // stage A: 128 rows x 32 k, transposed
      int fi = t + i * 256;
      int r = fi >> 3, kq = fi & 7;
      float4 v = *(const float4*)(A + (size_t)r * lda + k0 + ks + kq * 4);
      xs[kq*4+0][r] = v.x; xs[kq*4+1][r] = v.y;
      xs[kq*4+2][r] = v.z; xs[kq*4+3][r] = v.w;
    }
    #pragma unroll
    for (int i = 0; i < 2; ++i) {           // stage W: 32 k x 64 c
      int si = t + i * 256;
      int kk = si >> 4, cq = si & 15;
      *(float4*)&wsm[kk][cq*4] =
          *(const float4*)(W + (size_t)(k0 + ks + kk) * ldw + c0 + cq * 4);
    }
    __syncthreads();
    #pragma unroll
    for (int kk = 0; kk < 32; ++kk) {
      float a[8], bb[4];
      *(float4*)&a[0] = *(const float4*)&xs[kk][r0];
      *(float4*)&a[4] = *(const float4*)&xs[kk][r0 + 4];
      *(float4*)&bb[0] = *(const float4*)&wsm[kk][ct0];
      #pragma unroll
      for (int ii = 0; ii < 8; ++ii)
        #pragma unroll
        for (int jj = 0; jj < 4; ++jj)
          acc[ii][jj] = fmaf(a[ii], bb[jj], acc[ii][jj]);
    }
  }
  float* po = part + (size_t)blockIdx.y * 128 * ldw;
  #pragma unroll
  for (int ii = 0; ii < 8; ++ii)
    #pragma unroll
    for (int jj = 0; jj < 4; ++jj)
      po[(size_t)(r0 + ii) * ldw + c0 + ct0 + jj] = acc[ii][jj];
}

// ---------------- P2: reduce split-K partials + bias + RoPE ----------------
__global__ void ropefuse_kernel(const float* __restrict__ part,
                                const float* __restrict__ bias,
                                const int* __restrict__ cidx,
                                float* __restrict__ qh, float* __restrict__ kn,
                                float* __restrict__ vn)
{
  int gt = blockIdx.x * 256 + threadIdx.x;     // 65536 = 8*16*16*32
  int i = gt & 31, l = (gt >> 5) & 15, h = (gt >> 9) & 15, b = gt >> 13;
  int row = b * L_ + l;
  const int PS = 128 * 3072;
  const float* pr = part + (size_t)row * 3072;
  int cq = h * 64 + i;
  int cols[6] = {cq, cq + 32, 1024 + cq, 1024 + cq + 32, 2048 + cq, 2048 + cq + 32};
  float v[6];
  #pragma unroll
  for (int c = 0; c < 6; ++c) {
    float s = bias[cols[c]];
    #pragma unroll
    for (int ks = 0; ks < 4; ++ks) s += pr[(size_t)ks * PS + cols[c]];
    v[c] = s;
  }
  int pos = cidx[0] + l;
  float inv = exp2f((float)i * (-13.287712379549449f / 32.0f));
  float fr = (float)pos * inv;
  float sn, cs;
  sincosf(fr, &sn, &cs);
  int ob = ((b * H_ + h) * L_ + l) * 64;       // [B][H][L][D]
  qh[ob + i]      = (v[0] * cs - v[1] * sn) * 0.125f;
  qh[ob + 32 + i] = (v[1] * cs + v[0] * sn) * 0.125f;
  kn[ob + i]      = v[2] * cs - v[3] * sn;
  kn[ob + 32 + i] = v[3] * cs + v[2] * sn;
  vn[ob + i]      = v[4];
  vn[ob + 32 + i] = v[5];
}

// ---------------- P3: partial flash attention over the 8192 cache ----------
// grid (128 bh, 8 chunks) -- bh fastest so all 16 h of a (b,chunk) run
// concurrently across XCDs, keeping DRAM row-buffer locality on the 4KB rows.
// Register double-buffer (T14): issue tile t+1's loads before computing t.
__global__ void __launch_bounds__(256, 4) attn_partial_kernel(
    const float* __restrict__ qh, const float* __restrict__ kc,
    const float* __restrict__ vc, float* __restrict__ opart,
    float* __restrict__ mpart, float* __restrict__ lpart)
{
  const int bh = blockIdx.x;
  const int chunk = blockIdx.y;
  const int b = bh >> 4, h = bh & 15;
  const int tid = threadIdx.x;
  const int w = tid >> 6, lane = tid & 63;
  __shared__ float kt[64 * 64];   // 16 KB, K tile (slot-swizzled contents)
  __shared__ float vt[64 * 64];   // 16 KB, V tile linear
  __shared__ float ql[16 * 64];   // 4 KB (q pre-scaled)
  __shared__ float pl[16 * 64];   // 4 KB (per-wave private rows)
  {
    int l = tid >> 4, sl = tid & 15;
    *(float4*)&ql[l * 64 + sl * 4] = *(const float4*)&qh[(size_t)(bh * 16 + l) * 64 + sl * 4];
  }
  const int Lg = w * 4;
  float m_run[4], l_run[4], o[4];
  #pragma unroll
  for (int li = 0; li < 4; ++li) { m_run[li] = -1e30f; l_run[li] = 0.f; o[li] = 0.f; }
  const size_t base = (size_t)b * S_ * DM + (size_t)h * 64;
  const int s_base = chunk * 1024;

  float4 pk[4], pv[4];
#define ISSUE(TT) do {                                                        \
    const int st_ = s_base + (TT) * 64;                                       \
    _Pragma("unroll")                                                         \
    for (int i_ = 0; i_ < 4; ++i_) {                                          \
      int fi_ = tid + i_ * 256, r_ = fi_ >> 4, p_ = fi_ & 15;                 \
      int j_ = p_ ^ (r_ & 7);                                                 \
      const float* rp_ = kc + base + (size_t)(st_ + r_) * DM;                 \
      pk[i_] = *(const float4*)(rp_ + j_ * 4);                                \
      pv[i_] = *(const float4*)(vc + base + (size_t)(st_ + r_) * DM + p_ * 4);\
    } } while (0)
#define WRITE() do {                                                          \
    _Pragma("unroll")                                                         \
    for (int i_ = 0; i_ < 4; ++i_) {                                          \
      int fi_ = tid + i_ * 256, r_ = fi_ >> 4, p_ = fi_ & 15;                 \
      *(float4*)&kt[r_ * 64 + p_ * 4] = pk[i_];                               \
      *(float4*)&vt[r_ * 64 + p_ * 4] = pv[i_];                               \
    } } while (0)

  ISSUE(0);
  WRITE();
  __syncthreads();

  for (int tt = 0; tt < 16; ++tt) {
    if (tt < 15) ISSUE(tt + 1);      // next tile's loads in flight during compute
    // ---- phase A: scores, lane <-> s-row ----
    float sc[4] = {0.f, 0.f, 0.f, 0.f};
    #pragma unroll
    for (int dc = 0; dc < 16; ++dc) {
      int pp = dc ^ (lane & 7);
      float4 kv = *(const float4*)&kt[lane * 64 + pp * 4];
      #pragma unroll
      for (int li = 0; li < 4; ++li) {
        float4 qv = *(const float4*)&ql[(Lg + li) * 64 + dc * 4];
        sc[li] += kv.x * qv.x + kv.y * qv.y + kv.z * qv.z + kv.w * qv.w;
      }
    }
    // ---- online softmax (wave-wide butterfly) ----
    #pragma unroll
    for (int li = 0; li < 4; ++li) {
      float mx = sc[li];
      #pragma unroll
      for (int d = 1; d < 64; d <<= 1) mx = fmaxf(mx, __shfl_xor(mx, d));
      float m_new = fmaxf(m_run[li], mx);
      float c = __expf(m_run[li] - m_new);
      float p = __expf(sc[li] - m_new);
      float sm = p;
      #pragma unroll
      for (int d = 1; d < 64; d <<= 1) sm += __shfl_xor(sm, d);
      l_run[li] = l_run[li] * c + sm;
      m_run[li] = m_new;
      o[li] *= c;
      pl[(Lg + li) * 64 + lane] = p;  // same-wave transpose buffer
    }
    // ---- phase B: O += P*V, lane <-> d ----
    float pvr[4][4];
    #pragma unroll
    for (int s4 = 0; s4 < 16; ++s4) {
      #pragma unroll
      for (int li = 0; li < 4; ++li)
        *(float4*)&pvr[li][0] = *(const float4*)&pl[(Lg + li) * 64 + s4 * 4];
      #pragma unroll
      for (int j = 0; j < 4; ++j) {
        float vv = vt[(s4 * 4 + j) * 64 + lane];
        #pragma unroll
        for (int li = 0; li < 4; ++li) o[li] = fmaf(pvr[li][j], vv, o[li]);
      }
    }
    __syncthreads();                  // everyone done reading kt/vt
    if (tt < 15) WRITE();             // vmcnt wait happens here, post-compute
    __syncthreads();                  // new tile visible
  }
#undef ISSUE
#undef WRITE

  #pragma unroll
  for (int li = 0; li < 4; ++li)
    opart[(((size_t)chunk * 128 + bh) * 16 + Lg + li) * 64 + lane] = o[li];
  if (lane == 0) {
    #pragma unroll
    for (int li = 0; li < 4; ++li) {
      mpart[(chunk * 128 + bh) * 16 + Lg + li] = m_run[li];
      lpart[(chunk * 128 + bh) * 16 + Lg + li] = l_run[li];
    }
  }
}

// ---------------- P4: merge 8 chunk partials + 16 new tokens ---------------
__global__ void __launch_bounds__(64) combine_kernel(
    const float* __restrict__ qh, const float* __restrict__ kn,
    const float* __restrict__ vn, const float* __restrict__ opart,
    const float* __restrict__ mpart, const float* __restrict__ lpart,
    float* __restrict__ attn)
{
  const int bh = blockIdx.x;
  const int b = bh >> 4, h = bh & 15;
  const int lane = threadIdx.x;
  __shared__ float qb[1024], kb[1024], vb[1024];
  __shared__ float scn[16][16];
  for (int l = 0; l < 16; ++l) {
    qb[l * 64 + lane] = qh[(size_t)(bh * 16 + l) * 64 + lane];
    kb[l * 64 + lane] = kn[(size_t)(bh * 16 + l) * 64 + lane];
    vb[l * 64 + lane] = vn[(size_t)(bh * 16 + l) * 64 + lane];
  }
  __syncthreads();
  {
    int l = lane >> 2, sp0 = (lane & 3) * 4;
    for (int jj = 0; jj < 4; ++jj) {
      int sp = sp0 + jj;
      float a = 0.f;
      for (int d = 0; d < 64; ++d) a += qb[l * 64 + d] * kb[sp * 64 + d];
      scn[l][sp] = a;   // q already carries the 1/8 scale
    }
  }
  __syncthreads();
  for (int l = 0; l < 16; ++l) {
    float mc[8], lc[8];
    float m_tot = -1e30f;
    #pragma unroll
    for (int c = 0; c < 8; ++c) {
      mc[c] = mpart[(c * 128 + bh) * 16 + l];
      lc[c] = lpart[(c * 128 + bh) * 16 + l];
      m_tot = fmaxf(m_tot, mc[c]);
    }
    for (int sp = 0; sp < 16; ++sp) m_tot = fmaxf(m_tot, scn[l][sp]);
    float den = 0.f, od = 0.f;
    #pragma unroll
    for (int c = 0; c < 8; ++c) {
      float e = __expf(mc[c] - m_tot);
      den += lc[c] * e;
      od += opart[(((size_t)c * 128 + bh) * 16 + l) * 64 + lane] * e;
    }
    for (int sp = 0; sp < 16; ++sp) {
      float p = __expf(scn[l][sp] - m_tot);
      den += p;
      od += p * vb[sp * 64 + lane];
    }
    attn[((size_t)(b * 16 + l) * 16 + h) * 64 + lane] = od / den;
  }
}

// ---------------- P6: reduce O-proj split-K partials + bias ---------------
__global__ void reduce_out_kernel(const float* __restrict__ part2,
                                  const float* __restrict__ ob,
                                  float* __restrict__ out)
{
  int idx = blockIdx.x * 256 + threadIdx.x;  // 131072
  int c = idx & 1023;
  float s = ob[c];
  #pragma unroll
  for (int ks = 0; ks < 8; ++ks) s += part2[(size_t)ks * 131072 + idx];
  out[idx] = s;
}

extern "C" void kernel_launch(void* const* d_in, const int* in_sizes, int n_in,
                              void* d_out, int out_size, void* d_ws, size_t ws_size,
                              hipStream_t stream) {
  (void)in_sizes; (void)n_in; (void)out_size; (void)ws_size;
  const float* x       = (const float*)d_in[0];
  const float* cache_k = (const float*)d_in[1];
  const float* cache_v = (const float*)d_in[2];
  const float* qkv_w   = (const float*)d_in[3];
  const float* qkv_b   = (const float*)d_in[4];
  const float* o_w     = (const float*)d_in[5];
  const float* o_b     = (const float*)d_in[6];
  const int*   cidx    = (const int*)d_in[7];
  float* out = (float*)d_out;

  float* ws    = (float*)d_ws;
  float* part1 = ws;                     // 4*128*3072 = 1572864
  float* qh    = part1 + 1572864;        // 131072  [B][H][L][D], pre-scaled
  float* kn    = qh + 131072;            // 131072
  float* vn    = kn + 131072;            // 131072
  float* opart = vn + 131072;            // 8*128*16*64 = 1048576
  float* mpart = opart + 1048576;        // 16384
  float* lpart = mpart + 16384;          // 16384
  float* attn  = lpart + 16384;          // 131072
  float* part2 = attn + 131072;          // 8*128*1024 = 1048576

  // P1: qkv = x @ qkv_w (split-K 4)
  gemm_splitk_kernel<<<dim3(48, 4), 256, 0, stream>>>(x, qkv_w, part1, 1024, 3072, 256);
  // P2: reduce + bias + RoPE -> qh (scaled), kn, vn
  ropefuse_kernel<<<256, 256, 0, stream>>>(part1, qkv_b, cidx, qh, kn, vn);
  // P3: partial attention over the 8192-deep cache (bh fastest!)
  attn_partial_kernel<<<dim3(128, 8), 256, 0, stream>>>(qh, cache_k, cache_v,
                                                        opart, mpart, lpart);
  // P4: merge partials + 16 new tokens -> attn (128 x 1024)
  combine_kernel<<<128, 64, 0, stream>>>(qh, kn, vn, opart, mpart, lpart, attn);
  // P5: attn @ o_w (split-K 8)
  gemm_splitk_kernel<<<dim3(16, 8), 256, 0, stream>>>(attn, o_w, part2, 1024, 1024, 128);
  // P6: reduce + bias -> out
  reduce_out_kernel<<<512, 256, 0, stream>>>(part2, o_b, out);
}

// Round 3
// 487.452 us; speedup vs baseline: 4.1223x; 4.1223x over previous
//
#include <hip/hip_runtime.h>

#define B_ 8
#define L_ 16
#define H_ 16
#define D_ 64
#define DM 1024
#define S_ 8192

// direct global->LDS DMA, 16B per lane; LDS dest is wave-uniform base + lane*16
__device__ __forceinline__ void gld_lds16(const float* g, float* l) {
  __builtin_amdgcn_global_load_lds(
      (const __attribute__((address_space(1))) void*)g,
      (__attribute__((address_space(3))) void*)l, 16, 0, 0);
}

// ---------------- P1/P5: split-K GEMM, M=128, BN=64, BK=32 ----------------
__global__ void __launch_bounds__(256) gemm_splitk_kernel(
    const float* __restrict__ A, const float* __restrict__ W,
    float* __restrict__ part, int lda, int ldw, int Kchunk)
{
  const int c0 = blockIdx.x * 64;
  const int k0 = blockIdx.y * Kchunk;
  const int t  = threadIdx.x;
  __shared__ float xs[32][132];   // A tile transposed, padded
  __shared__ float wsm[32][64];   // W tile
  float acc[8][4];
  #pragma unroll
  for (int i = 0; i < 8; ++i)
    #pragma unroll
    for (int j = 0; j < 4; ++j) acc[i][j] = 0.f;
  const int rg = t >> 4, cg = t & 15;
  const int r0 = rg * 8, ct0 = cg * 4;
  for (int ks = 0; ks < Kchunk; ks += 32) {
    __syncthreads();
    #pragma unroll
    for (int i = 0; i < 4; ++i) {           // stage A: 128 rows x 32 k, transposed
      int fi = t + i * 256;
      int r = fi >> 3, kq = fi & 7;
      float4 v = *(const float4*)(A + (size_t)r * lda + k0 + ks + kq * 4);
      xs[kq*4+0][r] = v.x; xs[kq*4+1][r] = v.y;
      xs[kq*4+2][r] = v.z; xs[kq*4+3][r] = v.w;
    }
    #pragma unroll
    for (int i = 0; i < 2; ++i) {           // stage W: 32 k x 64 c
      int si = t + i * 256;
      int kk = si >> 4, cq = si & 15;
      *(float4*)&wsm[kk][cq*4] =
          *(const float4*)(W + (size_t)(k0 + ks + kk) * ldw + c0 + cq * 4);
    }
    __syncthreads();
    #pragma unroll
    for (int kk = 0; kk < 32; ++kk) {
      float a[8], bb[4];
      *(float4*)&a[0] = *(const float4*)&xs[kk][r0];
      *(float4*)&a[4] = *(const float4*)&xs[kk][r0 + 4];
      *(float4*)&bb[0] = *(const float4*)&wsm[kk][ct0];
      #pragma unroll
      for (int ii = 0; ii < 8; ++ii)
        #pragma unroll
        for (int jj = 0; jj < 4; ++jj)
          acc[ii][jj] = fmaf(a[ii], bb[jj], acc[ii][jj]);
    }
  }
  float* po = part + (size_t)blockIdx.y * 128 * ldw;
  #pragma unroll
  for (int ii = 0; ii < 8; ++ii)
    #pragma unroll
    for (int jj = 0; jj < 4; ++jj)
      po[(size_t)(r0 + ii) * ldw + c0 + ct0 + jj] = acc[ii][jj];
}

// ---------------- P2: reduce split-K partials + bias + RoPE ----------------
__global__ void ropefuse_kernel(const float* __restrict__ part,
                                const float* __restrict__ bias,
                                const int* __restrict__ cidx,
                                float* __restrict__ qh, float* __restrict__ kn,
                                float* __restrict__ vn)
{
  int gt = blockIdx.x * 256 + threadIdx.x;     // 65536 = 8*16*16*32
  int i = gt & 31, l = (gt >> 5) & 15, h = (gt >> 9) & 15, b = gt >> 13;
  int row = b * L_ + l;
  const int PS = 128 * 3072;
  const float* pr = part + (size_t)row * 3072;
  int cq = h * 64 + i;
  int cols[6] = {cq, cq + 32, 1024 + cq, 1024 + cq + 32, 2048 + cq, 2048 + cq + 32};
  float v[6];
  #pragma unroll
  for (int c = 0; c < 6; ++c) {
    float s = bias[cols[c]];
    #pragma unroll
    for (int ks = 0; ks < 4; ++ks) s += pr[(size_t)ks * PS + cols[c]];
    v[c] = s;
  }
  int pos = cidx[0] + l;
  float inv = exp2f((float)i * (-13.287712379549449f / 32.0f));
  float fr = (float)pos * inv;
  float sn, cs;
  sincosf(fr, &sn, &cs);
  int ob = ((b * H_ + h) * L_ + l) * 64;       // [B][H][L][D]
  qh[ob + i]      = (v[0] * cs - v[1] * sn) * 0.125f;
  qh[ob + 32 + i] = (v[1] * cs + v[0] * sn) * 0.125f;
  kn[ob + i]      = v[2] * cs - v[3] * sn;
  kn[ob + 32 + i] = v[3] * cs + v[2] * sn;
  vn[ob + i]      = v[4];
  vn[ob + 32 + i] = v[5];
}

// ---------------- P3: partial flash attention over the 8192 cache ----------
// grid (128 bh, 8 chunks), bh fastest. LDS double-buffer filled by
// global_load_lds (no VGPR staging -> no spill). K contents swizzled via
// pre-swizzled per-lane GLOBAL source address; LDS dest stays linear.
// Per tile: issue(t+1 -> buf^1) BEFORE compute(buf); the barrier's vmcnt(0)
// drain then lands a full compute phase after issue.
__global__ void __launch_bounds__(256) attn_partial_kernel(
    const float* __restrict__ qh, const float* __restrict__ kc,
    const float* __restrict__ vc, float* __restrict__ opart,
    float* __restrict__ mpart, float* __restrict__ lpart)
{
  const int bh = blockIdx.x;
  const int chunk = blockIdx.y;
  const int b = bh >> 4, h = bh & 15;
  const int tid = threadIdx.x;
  const int w = tid >> 6, lane = tid & 63;
  __shared__ float kt[2][64 * 64];   // 32 KB
  __shared__ float vt[2][64 * 64];   // 32 KB
  __shared__ float ql[16 * 64];      // 4 KB (q pre-scaled)
  __shared__ float pl[16 * 64];      // 4 KB (per-wave private rows)
  {
    int l = tid >> 4, sl = tid & 15;
    *(float4*)&ql[l * 64 + sl * 4] = *(const float4*)&qh[(size_t)(bh * 16 + l) * 64 + sl * 4];
  }
  const int Lg = w * 4;
  float m_run[4], l_run[4], o[4];
  #pragma unroll
  for (int li = 0; li < 4; ++li) { m_run[li] = -1e30f; l_run[li] = 0.f; o[li] = 0.f; }
  const size_t base = (size_t)b * S_ * DM + (size_t)h * 64;
  const int s_base = chunk * 1024;
  const int rowi = lane >> 4, p = lane & 15;

  // stage tile tt into buf: wave w covers rows [w*16, w*16+16), 4 rows/issue
  auto issue = [&](int tt, int buf) {
    const int st = s_base + tt * 64;
    #pragma unroll
    for (int i = 0; i < 4; ++i) {
      const int r0w = w * 16 + i * 4;          // wave-uniform LDS base row
      const int r = r0w + rowi;                // per-lane row
      const int jk = p ^ (r & 7);              // K source pre-swizzle
      gld_lds16(kc + base + (size_t)(st + r) * DM + jk * 4, &kt[buf][r0w * 64]);
      gld_lds16(vc + base + (size_t)(st + r) * DM + p * 4,  &vt[buf][r0w * 64]);
    }
  };

  issue(0, 0);
  __syncthreads();   // drains tile-0 DMA + ql write

  for (int tt = 0; tt < 16; ++tt) {
    const int cb = tt & 1;
    if (tt < 15) issue(tt + 1, cb ^ 1);   // in flight during compute
    // ---- phase A: scores, lane <-> s-row ----
    float sc[4] = {0.f, 0.f, 0.f, 0.f};
    #pragma unroll
    for (int dc = 0; dc < 16; ++dc) {
      int pp = dc ^ (lane & 7);
      float4 kv = *(const float4*)&kt[cb][lane * 64 + pp * 4];
      #pragma unroll
      for (int li = 0; li < 4; ++li) {
        float4 qv = *(const float4*)&ql[(Lg + li) * 64 + dc * 4];
        sc[li] += kv.x * qv.x + kv.y * qv.y + kv.z * qv.z + kv.w * qv.w;
      }
    }
    // ---- online softmax (wave-wide butterfly) ----
    #pragma unroll
    for (int li = 0; li < 4; ++li) {
      float mx = sc[li];
      #pragma unroll
      for (int d = 1; d < 64; d <<= 1) mx = fmaxf(mx, __shfl_xor(mx, d));
      float m_new = fmaxf(m_run[li], mx);
      float c = __expf(m_run[li] - m_new);
      float pex = __expf(sc[li] - m_new);
      float sm = pex;
      #pragma unroll
      for (int d = 1; d < 64; d <<= 1) sm += __shfl_xor(sm, d);
      l_run[li] = l_run[li] * c + sm;
      m_run[li] = m_new;
      o[li] *= c;
      pl[(Lg + li) * 64 + lane] = pex;  // same-wave transpose buffer
    }
    // ---- phase B: O += P*V, lane <-> d ----
    float pvr[4][4];
    #pragma unroll
    for (int s4 = 0; s4 < 16; ++s4) {
      #pragma unroll
      for (int li = 0; li < 4; ++li)
        *(float4*)&pvr[li][0] = *(const float4*)&pl[(Lg + li) * 64 + s4 * 4];
      #pragma unroll
      for (int j = 0; j < 4; ++j) {
        float vv = vt[cb][(s4 * 4 + j) * 64 + lane];
        #pragma unroll
        for (int li = 0; li < 4; ++li) o[li] = fmaf(pvr[li][j], vv, o[li]);
      }
    }
    __syncthreads();   // drains next-tile DMA (issued pre-compute) + guards buf reuse
  }

  #pragma unroll
  for (int li = 0; li < 4; ++li)
    opart[(((size_t)chunk * 128 + bh) * 16 + Lg + li) * 64 + lane] = o[li];
  if (lane == 0) {
    #pragma unroll
    for (int li = 0; li < 4; ++li) {
      mpart[(chunk * 128 + bh) * 16 + Lg + li] = m_run[li];
      lpart[(chunk * 128 + bh) * 16 + Lg + li] = l_run[li];
    }
  }
}

// ---------------- P4: merge 8 chunk partials + 16 new tokens ---------------
__global__ void __launch_bounds__(64) combine_kernel(
    const float* __restrict__ qh, const float* __restrict__ kn,
    const float* __restrict__ vn, const float* __restrict__ opart,
    const float* __restrict__ mpart, const float* __restrict__ lpart,
    float* __restrict__ attn)
{
  const int bh = blockIdx.x;
  const int b = bh >> 4, h = bh & 15;
  const int lane = threadIdx.x;
  __shared__ float qb[1024], kb[1024], vb[1024];
  __shared__ float scn[16][16];
  for (int l = 0; l < 16; ++l) {
    qb[l * 64 + lane] = qh[(size_t)(bh * 16 + l) * 64 + lane];
    kb[l * 64 + lane] = kn[(size_t)(bh * 16 + l) * 64 + lane];
    vb[l * 64 + lane] = vn[(size_t)(bh * 16 + l) * 64 + lane];
  }
  __syncthreads();
  {
    int l = lane >> 2, sp0 = (lane & 3) * 4;
    for (int jj = 0; jj < 4; ++jj) {
      int sp = sp0 + jj;
      float a = 0.f;
      for (int d = 0; d < 64; ++d) a += qb[l * 64 + d] * kb[sp * 64 + d];
      scn[l][sp] = a;   // q already carries the 1/8 scale
    }
  }
  __syncthreads();
  for (int l = 0; l < 16; ++l) {
    float mc[8], lc[8];
    float m_tot = -1e30f;
    #pragma unroll
    for (int c = 0; c < 8; ++c) {
      mc[c] = mpart[(c * 128 + bh) * 16 + l];
      lc[c] = lpart[(c * 128 + bh) * 16 + l];
      m_tot = fmaxf(m_tot, mc[c]);
    }
    for (int sp = 0; sp < 16; ++sp) m_tot = fmaxf(m_tot, scn[l][sp]);
    float den = 0.f, od = 0.f;
    #pragma unroll
    for (int c = 0; c < 8; ++c) {
      float e = __expf(mc[c] - m_tot);
      den += lc[c] * e;
      od += opart[(((size_t)c * 128 + bh) * 16 + l) * 64 + lane] * e;
    }
    for (int sp = 0; sp < 16; ++sp) {
      float pex = __expf(scn[l][sp] - m_tot);
      den += pex;
      od += pex * vb[sp * 64 + lane];
    }
    attn[((size_t)(b * 16 + l) * 16 + h) * 64 + lane] = od / den;
  }
}

// ---------------- P6: reduce O-proj split-K partials + bias ---------------
__global__ void reduce_out_kernel(const float* __restrict__ part2,
                                  const float* __restrict__ ob,
                                  float* __restrict__ out)
{
  int idx = blockIdx.x * 256 + threadIdx.x;  // 131072
  int c = idx & 1023;
  float s = ob[c];
  #pragma unroll
  for (int ks = 0; ks < 8; ++ks) s += part2[(size_t)ks * 131072 + idx];
  out[idx] = s;
}

extern "C" void kernel_launch(void* const* d_in, const int* in_sizes, int n_in,
                              void* d_out, int out_size, void* d_ws, size_t ws_size,
                              hipStream_t stream) {
  (void)in_sizes; (void)n_in; (void)out_size; (void)ws_size;
  const float* x       = (const float*)d_in[0];
  const float* cache_k = (const float*)d_in[1];
  const float* cache_v = (const float*)d_in[2];
  const float* qkv_w   = (const float*)d_in[3];
  const float* qkv_b   = (const float*)d_in[4];
  const float* o_w     = (const float*)d_in[5];
  const float* o_b     = (const float*)d_in[6];
  const int*   cidx    = (const int*)d_in[7];
  float* out = (float*)d_out;

  float* ws    = (float*)d_ws;
  float* part1 = ws;                     // 4*128*3072 = 1572864
  float* qh    = part1 + 1572864;        // 131072  [B][H][L][D], pre-scaled
  float* kn    = qh + 131072;            // 131072
  float* vn    = kn + 131072;            // 131072
  float* opart = vn + 131072;            // 8*128*16*64 = 1048576
  float* mpart = opart + 1048576;        // 16384
  float* lpart = mpart + 16384;          // 16384
  float* attn  = lpart + 16384;          // 131072
  float* part2 = attn + 131072;          // 8*128*1024 = 1048576

  // P1: qkv = x @ qkv_w (split-K 4)
  gemm_splitk_kernel<<<dim3(48, 4), 256, 0, stream>>>(x, qkv_w, part1, 1024, 3072, 256);
  // P2: reduce + bias + RoPE -> qh (scaled), kn, vn
  ropefuse_kernel<<<256, 256, 0, stream>>>(part1, qkv_b, cidx, qh, kn, vn);
  // P3: partial attention over the 8192-deep cache (bh fastest)
  attn_partial_kernel<<<dim3(128, 8), 256, 0, stream>>>(qh, cache_k, cache_v,
                                                        opart, mpart, lpart);
  // P4: merge partials + 16 new tokens -> attn (128 x 1024)
  combine_kernel<<<128, 64, 0, stream>>>(qh, kn, vn, opart, mpart, lpart, attn);
  // P5: attn @ o_w (split-K 8)
  gemm_splitk_kernel<<<dim3(16, 8), 256, 0, stream>>>(attn, o_w, part2, 1024, 1024, 128);
  // P6: reduce + bias -> out
  reduce_out_kernel<<<512, 256, 0, stream>>>(part2, o_b, out);
}

// Round 4
// 225.617 us; speedup vs baseline: 8.9064x; 2.1605x over previous
//
#include <hip/hip_runtime.h>

#define B_ 8
#define L_ 16
#define H_ 16
#define D_ 64
#define DM 1024
#define S_ 8192

// direct global->LDS DMA, 16B per lane; LDS dest is wave-uniform base + lane*16
__device__ __forceinline__ void gld_lds16(const float* g, float* l) {
  __builtin_amdgcn_global_load_lds(
      (const __attribute__((address_space(1))) void*)g,
      (__attribute__((address_space(3))) void*)l, 16, 0, 0);
}

// ---------------- P1/P5: split-K GEMM, M=128, BN=64, BK=32 ----------------
__global__ void __launch_bounds__(256) gemm_splitk_kernel(
    const float* __restrict__ A, const float* __restrict__ W,
    float* __restrict__ part, int lda, int ldw, int Kchunk)
{
  const int c0 = blockIdx.x * 64;
  const int k0 = blockIdx.y * Kchunk;
  const int t  = threadIdx.x;
  __shared__ float xs[32][132];   // A tile transposed, padded
  __shared__ float wsm[32][64];   // W tile
  float acc[8][4];
  #pragma unroll
  for (int i = 0; i < 8; ++i)
    #pragma unroll
    for (int j = 0; j < 4; ++j) acc[i][j] = 0.f;
  const int rg = t >> 4, cg = t & 15;
  const int r0 = rg * 8, ct0 = cg * 4;
  for (int ks = 0; ks < Kchunk; ks += 32) {
    __syncthreads();
    #pragma unroll
    for (int i = 0; i < 4; ++i) {           // stage A: 128 rows x 32 k, transposed
      int fi = t + i * 256;
      int r = fi >> 3, kq = fi & 7;
      float4 v = *(const float4*)(A + (size_t)r * lda + k0 + ks + kq * 4);
      xs[kq*4+0][r] = v.x; xs[kq*4+1][r] = v.y;
      xs[kq*4+2][r] = v.z; xs[kq*4+3][r] = v.w;
    }
    #pragma unroll
    for (int i = 0; i < 2; ++i) {           // stage W: 32 k x 64 c
      int si = t + i * 256;
      int kk = si >> 4, cq = si & 15;
      *(float4*)&wsm[kk][cq*4] =
          *(const float4*)(W + (size_t)(k0 + ks + kk) * ldw + c0 + cq * 4);
    }
    __syncthreads();
    #pragma unroll
    for (int kk = 0; kk < 32; ++kk) {
      float a[8], bb[4];
      *(float4*)&a[0] = *(const float4*)&xs[kk][r0];
      *(float4*)&a[4] = *(const float4*)&xs[kk][r0 + 4];
      *(float4*)&bb[0] = *(const float4*)&wsm[kk][ct0];
      #pragma unroll
      for (int ii = 0; ii < 8; ++ii)
        #pragma unroll
        for (int jj = 0; jj < 4; ++jj)
          acc[ii][jj] = fmaf(a[ii], bb[jj], acc[ii][jj]);
    }
  }
  float* po = part + (size_t)blockIdx.y * 128 * ldw;
  #pragma unroll
  for (int ii = 0; ii < 8; ++ii)
    #pragma unroll
    for (int jj = 0; jj < 4; ++jj)
      po[(size_t)(r0 + ii) * ldw + c0 + ct0 + jj] = acc[ii][jj];
}

// ---------------- P2: reduce split-K partials + bias + RoPE ----------------
__global__ void ropefuse_kernel(const float* __restrict__ part,
                                const float* __restrict__ bias,
                                const int* __restrict__ cidx,
                                float* __restrict__ qh, float* __restrict__ kn,
                                float* __restrict__ vn)
{
  int gt = blockIdx.x * 256 + threadIdx.x;     // 65536 = 8*16*16*32
  int i = gt & 31, l = (gt >> 5) & 15, h = (gt >> 9) & 15, b = gt >> 13;
  int row = b * L_ + l;
  const int PS = 128 * 3072;
  const float* pr = part + (size_t)row * 3072;
  int cq = h * 64 + i;
  int cols[6] = {cq, cq + 32, 1024 + cq, 1024 + cq + 32, 2048 + cq, 2048 + cq + 32};
  float v[6];
  #pragma unroll
  for (int c = 0; c < 6; ++c) {
    float s = bias[cols[c]];
    #pragma unroll
    for (int ks = 0; ks < 4; ++ks) s += pr[(size_t)ks * PS + cols[c]];
    v[c] = s;
  }
  int pos = cidx[0] + l;
  float inv = exp2f((float)i * (-13.287712379549449f / 32.0f));
  float fr = (float)pos * inv;
  float sn, cs;
  sincosf(fr, &sn, &cs);
  int ob = ((b * H_ + h) * L_ + l) * 64;       // [B][H][L][D]
  qh[ob + i]      = (v[0] * cs - v[1] * sn) * 0.125f;
  qh[ob + 32 + i] = (v[1] * cs + v[0] * sn) * 0.125f;
  kn[ob + i]      = v[2] * cs - v[3] * sn;
  kn[ob + 32 + i] = v[3] * cs + v[2] * sn;
  vn[ob + i]      = v[4];
  vn[ob + 32 + i] = v[5];
}

// ---------------- P3: partial flash attention over the 8192 cache ----------
// DMA double-buffer with COUNTED vmcnt waits (T4): each wave issues exactly
// 8 global_load_lds per tile; s_waitcnt vmcnt(8) + raw s_barrier lets tile
// t+1's loads stay in flight across both barriers (never drain to 0 in-loop).
// Phase B: lane <-> (d-quad, s-quarter) -> V read as b128, P as b32 broadcast.
__global__ void __launch_bounds__(256) attn_partial_kernel(
    const float* __restrict__ qh, const float* __restrict__ kc,
    const float* __restrict__ vc, float* __restrict__ opart,
    float* __restrict__ mpart, float* __restrict__ lpart)
{
  const int bh = blockIdx.x;
  const int chunk = blockIdx.y;
  const int b = bh >> 4, h = bh & 15;
  const int tid = threadIdx.x;
  const int w = tid >> 6, lane = tid & 63;
  __shared__ float kt[2][64 * 64];   // 32 KB
  __shared__ float vt[2][64 * 64];   // 32 KB
  __shared__ float ql[16 * 64];      // 4 KB (q pre-scaled)
  __shared__ float pl[16 * 64];      // 4 KB (per-wave private rows)
  {
    int l = tid >> 4, sl = tid & 15;
    *(float4*)&ql[l * 64 + sl * 4] = *(const float4*)&qh[(size_t)(bh * 16 + l) * 64 + sl * 4];
  }
  const int Lg = w * 4;
  const int rowi = lane >> 4, p = lane & 15;   // staging roles
  const int sq = rowi, dq = p;                 // phase-B roles (same split)
  float m_run[4], l_run[4];
  float4 op[4];
  #pragma unroll
  for (int li = 0; li < 4; ++li) {
    m_run[li] = -1e30f; l_run[li] = 0.f;
    op[li].x = op[li].y = op[li].z = op[li].w = 0.f;
  }
  const size_t base = (size_t)b * S_ * DM + (size_t)h * 64;
  const int s_base = chunk * 1024;

  // stage tile tt into buf: wave w covers rows [w*16, w*16+16), exactly 8 DMAs
  auto issue = [&](int tt, int buf) {
    const int st = s_base + tt * 64;
    #pragma unroll
    for (int i = 0; i < 4; ++i) {
      const int r0w = w * 16 + i * 4;          // wave-uniform LDS base row
      const int r = r0w + rowi;                // per-lane row
      const int jk = p ^ (r & 7);              // K source pre-swizzle
      gld_lds16(kc + base + (size_t)(st + r) * DM + jk * 4, &kt[buf][r0w * 64]);
      gld_lds16(vc + base + (size_t)(st + r) * DM + p * 4,  &vt[buf][r0w * 64]);
    }
  };

  issue(0, 0);
  __syncthreads();   // one full drain: tile0 DMA + ql ds_writes visible

  for (int tt = 0; tt < 16; ++tt) {
    const int cb = tt & 1;
    if (tt < 15) {
      issue(tt + 1, cb ^ 1);                         // 8 loads -> in flight
      asm volatile("s_waitcnt vmcnt(8)" ::: "memory"); // tile tt landed
    } else {
      asm volatile("s_waitcnt vmcnt(0)" ::: "memory");
    }
    __builtin_amdgcn_sched_barrier(0);
    __builtin_amdgcn_s_barrier();                    // raw: no vmcnt(0) drain

    // ---- phase A: scores, lane <-> s-row ----
    float sc[4] = {0.f, 0.f, 0.f, 0.f};
    #pragma unroll
    for (int dc = 0; dc < 16; ++dc) {
      int pp = dc ^ (lane & 7);
      float4 kv = *(const float4*)&kt[cb][lane * 64 + pp * 4];
      #pragma unroll
      for (int li = 0; li < 4; ++li) {
        float4 qv = *(const float4*)&ql[(Lg + li) * 64 + dc * 4];
        sc[li] += kv.x * qv.x + kv.y * qv.y + kv.z * qv.z + kv.w * qv.w;
      }
    }
    // ---- online softmax (wave-wide butterfly) ----
    #pragma unroll
    for (int li = 0; li < 4; ++li) {
      float mx = sc[li];
      #pragma unroll
      for (int d = 1; d < 64; d <<= 1) mx = fmaxf(mx, __shfl_xor(mx, d));
      float m_new = fmaxf(m_run[li], mx);
      float c = __expf(m_run[li] - m_new);
      float pex = __expf(sc[li] - m_new);
      float sm = pex;
      #pragma unroll
      for (int d = 1; d < 64; d <<= 1) sm += __shfl_xor(sm, d);
      l_run[li] = l_run[li] * c + sm;
      m_run[li] = m_new;
      op[li].x *= c; op[li].y *= c; op[li].z *= c; op[li].w *= c;
      pl[(Lg + li) * 64 + lane] = pex;  // same-wave transpose buffer
    }
    // ---- phase B: lane = (sq, dq); o_p[li][4d] over lane's 16 s ----
    #pragma unroll
    for (int jj = 0; jj < 16; ++jj) {
      int s = sq * 16 + jj;
      float4 vv = *(const float4*)&vt[cb][s * 64 + dq * 4];
      #pragma unroll
      for (int li = 0; li < 4; ++li) {
        float pp = pl[(Lg + li) * 64 + s];
        op[li].x = fmaf(pp, vv.x, op[li].x);
        op[li].y = fmaf(pp, vv.y, op[li].y);
        op[li].z = fmaf(pp, vv.z, op[li].z);
        op[li].w = fmaf(pp, vv.w, op[li].w);
      }
    }
    __builtin_amdgcn_s_barrier();                    // all done reading cb
  }

  // ---- epilogue: reduce o_p across the 4 s-quarters (wave-private slice) ---
  #pragma unroll
  for (int li = 0; li < 4; ++li) {
    *(float4*)&pl[w * 256 + lane * 4] = op[li];      // slice[srclane][j]
    float s = 0.f;
    #pragma unroll
    for (int g = 0; g < 4; ++g) s += pl[w * 256 + g * 64 + lane];
    opart[(((size_t)chunk * 128 + bh) * 16 + Lg + li) * 64 + lane] = s;
  }
  if (lane == 0) {
    #pragma unroll
    for (int li = 0; li < 4; ++li) {
      mpart[(chunk * 128 + bh) * 16 + Lg + li] = m_run[li];
      lpart[(chunk * 128 + bh) * 16 + Lg + li] = l_run[li];
    }
  }
}

// ---------------- P4: merge 8 chunk partials + 16 new tokens ---------------
__global__ void __launch_bounds__(64) combine_kernel(
    const float* __restrict__ qh, const float* __restrict__ kn,
    const float* __restrict__ vn, const float* __restrict__ opart,
    const float* __restrict__ mpart, const float* __restrict__ lpart,
    float* __restrict__ attn)
{
  const int bh = blockIdx.x;
  const int b = bh >> 4, h = bh & 15;
  const int lane = threadIdx.x;
  __shared__ float qb[1024], kb[1024], vb[1024];
  __shared__ float scn[16][16];
  for (int l = 0; l < 16; ++l) {
    qb[l * 64 + lane] = qh[(size_t)(bh * 16 + l) * 64 + lane];
    kb[l * 64 + lane] = kn[(size_t)(bh * 16 + l) * 64 + lane];
    vb[l * 64 + lane] = vn[(size_t)(bh * 16 + l) * 64 + lane];
  }
  __syncthreads();
  {
    int l = lane >> 2, sp0 = (lane & 3) * 4;
    for (int jj = 0; jj < 4; ++jj) {
      int sp = sp0 + jj;
      float a = 0.f;
      for (int d = 0; d < 64; ++d) a += qb[l * 64 + d] * kb[sp * 64 + d];
      scn[l][sp] = a;   // q already carries the 1/8 scale
    }
  }
  __syncthreads();
  for (int l = 0; l < 16; ++l) {
    float mc[8], lc[8];
    float m_tot = -1e30f;
    #pragma unroll
    for (int c = 0; c < 8; ++c) {
      mc[c] = mpart[(c * 128 + bh) * 16 + l];
      lc[c] = lpart[(c * 128 + bh) * 16 + l];
      m_tot = fmaxf(m_tot, mc[c]);
    }
    for (int sp = 0; sp < 16; ++sp) m_tot = fmaxf(m_tot, scn[l][sp]);
    float den = 0.f, od = 0.f;
    #pragma unroll
    for (int c = 0; c < 8; ++c) {
      float e = __expf(mc[c] - m_tot);
      den += lc[c] * e;
      od += opart[(((size_t)c * 128 + bh) * 16 + l) * 64 + lane] * e;
    }
    for (int sp = 0; sp < 16; ++sp) {
      float pex = __expf(scn[l][sp] - m_tot);
      den += pex;
      od += pex * vb[sp * 64 + lane];
    }
    attn[((size_t)(b * 16 + l) * 16 + h) * 64 + lane] = od / den;
  }
}

// ---------------- P6: reduce O-proj split-K partials + bias ---------------
__global__ void reduce_out_kernel(const float* __restrict__ part2,
                                  const float* __restrict__ ob,
                                  float* __restrict__ out)
{
  int idx = blockIdx.x * 256 + threadIdx.x;  // 131072
  int c = idx & 1023;
  float s = ob[c];
  #pragma unroll
  for (int ks = 0; ks < 8; ++ks) s += part2[(size_t)ks * 131072 + idx];
  out[idx] = s;
}

extern "C" void kernel_launch(void* const* d_in, const int* in_sizes, int n_in,
                              void* d_out, int out_size, void* d_ws, size_t ws_size,
                              hipStream_t stream) {
  (void)in_sizes; (void)n_in; (void)out_size; (void)ws_size;
  const float* x       = (const float*)d_in[0];
  const float* cache_k = (const float*)d_in[1];
  const float* cache_v = (const float*)d_in[2];
  const float* qkv_w   = (const float*)d_in[3];
  const float* qkv_b   = (const float*)d_in[4];
  const float* o_w     = (const float*)d_in[5];
  const float* o_b     = (const float*)d_in[6];
  const int*   cidx    = (const int*)d_in[7];
  float* out = (float*)d_out;

  float* ws    = (float*)d_ws;
  float* part1 = ws;                     // 4*128*3072 = 1572864
  float* qh    = part1 + 1572864;        // 131072  [B][H][L][D], pre-scaled
  float* kn    = qh + 131072;            // 131072
  float* vn    = kn + 131072;            // 131072
  float* opart = vn + 131072;            // 8*128*16*64 = 1048576
  float* mpart = opart + 1048576;        // 16384
  float* lpart = mpart + 16384;          // 16384
  float* attn  = lpart + 16384;          // 131072
  float* part2 = attn + 131072;          // 8*128*1024 = 1048576

  // P1: qkv = x @ qkv_w (split-K 4)
  gemm_splitk_kernel<<<dim3(48, 4), 256, 0, stream>>>(x, qkv_w, part1, 1024, 3072, 256);
  // P2: reduce + bias + RoPE -> qh (scaled), kn, vn
  ropefuse_kernel<<<256, 256, 0, stream>>>(part1, qkv_b, cidx, qh, kn, vn);
  // P3: partial attention over the 8192-deep cache (bh fastest)
  attn_partial_kernel<<<dim3(128, 8), 256, 0, stream>>>(qh, cache_k, cache_v,
                                                        opart, mpart, lpart);
  // P4: merge partials + 16 new tokens -> attn (128 x 1024)
  combine_kernel<<<128, 64, 0, stream>>>(qh, kn, vn, opart, mpart, lpart, attn);
  // P5: attn @ o_w (split-K 8)
  gemm_splitk_kernel<<<dim3(16, 8), 256, 0, stream>>>(attn, o_w, part2, 1024, 1024, 128);
  // P6: reduce + bias -> out
  reduce_out_kernel<<<512, 256, 0, stream>>>(part2, o_b, out);
}